// Round 3
// baseline (594.094 us; speedup 1.0000x reference)
//
#include <hip/hip_runtime.h>

// PlasticSynapse elementwise update:
//   new_w = clip(baseline*ALPHA + w*(1-ALPHA)
//                + R[b] * |kappa[o,i]| * (post[b,o]*pre[b,i] + SIGMA*noise),
//                0, 1)
// Shapes: w,noise,out: (B,OUT,IN); baseline,kappa: (OUT,IN); pre: (B,IN);
//         post: (B,OUT); R: (B,1,1).  B=64, OUT=1024, IN=1024, all fp32.
//
// Round-3 design: b-inner loop with hoisted baseline/kappa (cuts cache-level
// request volume 33%) + explicit depth-2 software pipeline with NAMED
// current/next register sets (round-1 lesson: unrolled loops without explicit
// rotation get register-starved and serialize). One contiguous stream front
// per b-half (round-2 lesson: split fronts cost +52 MB FETCH).
//   grid = 1024 o-blocks x 2 b-halves = 2048 blocks = exactly 8 blocks/CU;
//   __launch_bounds__(256,8) pins VGPR<=64 -> 32 waves/CU.

constexpr int B_DIM  = 64;
constexpr int OUT_D  = 1024;
constexpr int IN_D   = 1024;
constexpr int IN4    = IN_D / 4;            // 256 float4 per row
constexpr int BLOCK  = 256;
constexpr int BSPLIT = 2;                   // b-range halves
constexpr int BITER  = B_DIM / BSPLIT;      // 32 iterations per thread
constexpr int GRID   = OUT_D * BSPLIT;      // 2048 blocks
constexpr int STEP   = OUT_D * IN4;         // float4 stride per b (=2^18)

constexpr float ALPHA  = 0.01f;             // DT_W / TAU_W
constexpr float ONE_MA = 1.0f - ALPHA;      // 0.99
constexpr float SIGMA  = 0.14142135623730951f; // sqrt(2/ALPHA)*0.01

__device__ __forceinline__ float4 upd(const float4 wv, const float4 nv,
                                      const float4 pr, const float po,
                                      const float r,
                                      const float4 ak, const float4 blA)
{
    float4 res;
    res.x = fminf(fmaxf(fmaf(r * ak.x, fmaf(SIGMA, nv.x, po * pr.x),
                             fmaf(wv.x, ONE_MA, blA.x)), 0.0f), 1.0f);
    res.y = fminf(fmaxf(fmaf(r * ak.y, fmaf(SIGMA, nv.y, po * pr.y),
                             fmaf(wv.y, ONE_MA, blA.y)), 0.0f), 1.0f);
    res.z = fminf(fmaxf(fmaf(r * ak.z, fmaf(SIGMA, nv.z, po * pr.z),
                             fmaf(wv.z, ONE_MA, blA.z)), 0.0f), 1.0f);
    res.w = fminf(fmaxf(fmaf(r * ak.w, fmaf(SIGMA, nv.w, po * pr.w),
                             fmaf(wv.w, ONE_MA, blA.w)), 0.0f), 1.0f);
    return res;
}

__global__ __launch_bounds__(BLOCK, 8)
void PlasticSynapse_69466801045994_kernel(
    const float4* __restrict__ w,
    const float4* __restrict__ baseline,
    const float*  __restrict__ R,
    const float4* __restrict__ pre,
    const float*  __restrict__ post,
    const float4* __restrict__ kappa,
    const float4* __restrict__ noise,
    float4*       __restrict__ out)
{
    const int o    = (int)blockIdx.x >> 1;      // 0..1023
    const int bh   = (int)blockIdx.x & 1;       // 0 or 1
    const int i4   = (int)threadIdx.x;          // 0..255
    const int b0   = bh * BITER;
    const int bend = b0 + BITER;

    // Hoisted: loaded ONCE per thread (vs 32x at cache level in round 0).
    const int oi = o * IN4 + i4;
    const float4 bl = baseline[oi];
    const float4 kp = kappa[oi];
    float4 ak, blA;
    ak.x  = fabsf(kp.x);  ak.y  = fabsf(kp.y);
    ak.z  = fabsf(kp.z);  ak.w  = fabsf(kp.w);
    blA.x = bl.x * ALPHA; blA.y = bl.y * ALPHA;
    blA.z = bl.z * ALPHA; blA.w = bl.w * ALPHA;

    // Depth-2 pipeline: named Current / Next register sets (all static).
    int idxC = (b0 * OUT_D + o) * IN4 + i4;

    float4 wC  = w[idxC];
    float4 nC  = noise[idxC];
    float4 pC  = pre[b0 * IN4 + i4];
    float  poC = post[b0 * OUT_D + o];
    float  rC  = R[b0];

    for (int b = b0; b < bend; ++b) {
        // Prefetch next iteration (clamped on last trip; values unused).
        const bool last = (b + 1 >= bend);
        const int  bn   = last ? b : b + 1;
        const int  idxN = idxC + (last ? 0 : STEP);

        const float4 wN  = w[idxN];
        const float4 nN  = noise[idxN];
        const float4 pN  = pre[bn * IN4 + i4];
        const float  poN = post[bn * OUT_D + o];
        const float  rN  = R[bn];

        // Compute + store current (its loads were issued one trip ago).
        out[idxC] = upd(wC, nC, pC, poC, rC, ak, blA);

        // Rotate.
        wC = wN; nC = nN; pC = pN; poC = poN; rC = rN; idxC = idxN;
    }
}

extern "C" void kernel_launch(void* const* d_in, const int* in_sizes, int n_in,
                              void* d_out, int out_size, void* d_ws, size_t ws_size,
                              hipStream_t stream) {
    // setup_inputs() dict order: w, baseline, R, pre, post, kappa, noise
    const float4* w        = (const float4*)d_in[0];
    const float4* baseline = (const float4*)d_in[1];
    const float*  R        = (const float*) d_in[2];
    const float4* pre      = (const float4*)d_in[3];
    const float*  post     = (const float*) d_in[4];
    const float4* kappa    = (const float4*)d_in[5];
    const float4* noise    = (const float4*)d_in[6];
    float4*       out      = (float4*)d_out;

    PlasticSynapse_69466801045994_kernel<<<GRID, BLOCK, 0, stream>>>(
        w, baseline, R, pre, post, kappa, noise, out);
}